// Round 4
// baseline (181.241 us; speedup 1.0000x reference)
//
#include <hip/hip_runtime.h>

#define LSEQ 1024
#define NB   2
#define NH   8
#define DD   64
#define DMOD 768

using bf16x8 = __attribute__((ext_vector_type(8))) short;
using f32x4  = __attribute__((ext_vector_type(4))) float;

__device__ inline unsigned short f2bf(float f) {
    union { float f; unsigned u; } v; v.f = f;
    unsigned r = v.u + 0x7FFFu + ((v.u >> 16) & 1u);
    return (unsigned short)(r >> 16);
}
__device__ inline float bf2f(unsigned short u) {
    union { unsigned u; float f; } v; v.u = ((unsigned)u) << 16;
    return v.f;
}

// ---------------------------------------------------------------------------
// pack x + Wq|Wk|Wv + Wo to bf16; block 3072 does the setup work:
//   wsfx[h][n] = (suffix(v.w_pos) - suffix(u.w_pos))/8, cls LUT, wpt bf16 [h][n][d]
// ---------------------------------------------------------------------------
__global__ __launch_bounds__(256) void pack_setup(
    const float4* __restrict__ x,  const float4* __restrict__ wq,
    const float4* __restrict__ wk, const float4* __restrict__ wv,
    const float4* __restrict__ wo,
    const float* __restrict__ u_bias, const float* __restrict__ v_bias,
    const float* __restrict__ w_pos,
    ushort4* __restrict__ xb, ushort4* __restrict__ wqb, ushort4* __restrict__ wkb,
    ushort4* __restrict__ wvb, ushort4* __restrict__ wob,
    float* __restrict__ wsfx, unsigned char* __restrict__ cls_g,
    unsigned short* __restrict__ wpt)
{
    if (blockIdx.x == 3072) {
        __shared__ float w_s[32];
        __shared__ float vw_s[8][64];
        __shared__ float uw_s[8][64];
        __shared__ int cmin_s[1024];
        int tid = threadIdx.x;
        if (tid < 32) {
            float pr = expf(logf(512.5f) / 32.0f);
            w_s[tid] = powf(pr, (float)(tid + 1));
        }
        __syncthreads();
        for (int d = tid; d < 1024; d += 256) {
            float fd = (float)d;
            int cm = 32;
            for (int c = 31; c >= 0; --c) if (fd <= w_s[c]) cm = c;
            cmin_s[d] = cm;
        }
        for (int idx = tid; idx < 512; idx += 256) {
            int hh = idx >> 6, n = idx & 63;
            float vs = 0.f, us = 0.f;
            for (int d = 0; d < 64; ++d) {
                float wp = w_pos[(hh * 64 + d) * 64 + n];
                vs += v_bias[hh * 64 + d] * wp;
                us += u_bias[hh * 64 + d] * wp;
            }
            vw_s[hh][n] = vs;
            uw_s[hh][n] = us;
        }
        __syncthreads();
        for (int idx = tid; idx < 512; idx += 256) {
            int hh = idx >> 6, n = idx & 63;
            float vs = 0.f, us = 0.f;
            if (n < 32) {
                for (int c = n; c < 32; ++c) { vs += vw_s[hh][c]; us += uw_s[hh][c]; }
            } else {
                for (int c = n - 32; c < 32; ++c) { vs += vw_s[hh][32 + c]; us += uw_s[hh][32 + c]; }
            }
            wsfx[idx] = (vs - us) * 0.125f;
        }
        for (int d2 = tid; d2 < 2048; d2 += 256) {
            int dd = d2 - 1023;
            int ad = dd < 0 ? -dd : dd; if (ad > 1023) ad = 1023;
            int t = (dd < 0) ? 0 : ((dd == 0) ? 1 : 2);
            cls_g[d2] = (unsigned char)(t * 33 + cmin_s[ad]);
        }
        // wpt[h][n][d] = bf16(w_pos[h][d][n])
        for (int idx = tid; idx < 32768; idx += 256) {
            int hh = idx >> 12, n = (idx >> 6) & 63, d = idx & 63;
            wpt[idx] = f2bf(w_pos[(hh * 64 + d) * 64 + n]);
        }
        return;
    }
    int i = blockIdx.x * 256 + threadIdx.x;
    const float4* src; ushort4* dst; int off;
    if (i < 393216)      { src = x;  dst = xb;  off = i; }
    else if (i < 491520) { src = wq; dst = wqb; off = i - 393216; }
    else if (i < 589824) { src = wk; dst = wkb; off = i - 491520; }
    else if (i < 688128) { src = wv; dst = wvb; off = i - 589824; }
    else                 { src = wo; dst = wob; off = i - 688128; }
    float4 v = src[off];
    ushort4 o;
    o.x = f2bf(v.x); o.y = f2bf(v.y); o.z = f2bf(v.z); o.w = f2bf(v.w);
    dst[off] = o;
}

// ---------------------------------------------------------------------------
// fused QKV projection GEMM: [2048x768] @ [1536x768]^T, 64x64 tile, 4 waves
//   n <  512: Q' = (q + u_bias)/8 -> bf16 [bh][i][d]; epilogue computes
//             qsfx[bh][i][n] = suffix_n((q+u).w_pos)/8 via MFMA vs wpt
//   n < 1024: K  -> bf16 [bh][j][d]
//   else    : V  -> bf16 transposed [bh][d][j]
// ---------------------------------------------------------------------------
__global__ __launch_bounds__(256) void gemm_qkv(
    const unsigned short* __restrict__ X, const unsigned short* __restrict__ W,
    const float* __restrict__ ub, const unsigned short* __restrict__ wpt,
    unsigned short* __restrict__ Qb, unsigned short* __restrict__ Kb,
    unsigned short* __restrict__ Vtb, float* __restrict__ qsfx)
{
    __shared__ unsigned short Xs[64][40];
    __shared__ unsigned short Wsm[64][40];
    __shared__ unsigned short Ct[64][72];
    __shared__ unsigned short wpt_s[64][64];   // [n][d] bf16, Q blocks only
    __shared__ float qwf[64][68];              // [row][n] fp32, Q blocks only

    int tid = threadIdx.x;
    int w = tid >> 6, lane = tid & 63, l15 = lane & 15, q = lane >> 4;
    int M0 = blockIdx.y * 64, N0 = blockIdx.x * 64;
    int rs = tid >> 2, seg = tid & 3;
    int isQ = (N0 < 512);
    int h = N0 >> 6;   // head for Q path

    if (isQ) {
        // stage wpt[h] (4096 shorts): 16 shorts per thread
        const ushort4* src = (const ushort4*)(wpt + h * 4096);
#pragma unroll
        for (int t = 0; t < 4; ++t)
            ((ushort4*)wpt_s)[tid * 4 + t] = src[tid * 4 + t];
    }

    f32x4 acc[4] = {};
    for (int k0 = 0; k0 < 768; k0 += 32) {
        uint4 xv = *(const uint4*)(X + (size_t)(M0 + rs) * 768 + k0 + seg * 8);
        uint4 wv = *(const uint4*)(W + (size_t)(N0 + rs) * 768 + k0 + seg * 8);
        *(uint4*)&Xs[rs][seg * 8]  = xv;
        *(uint4*)&Wsm[rs][seg * 8] = wv;
        __syncthreads();
        bf16x8 a = *(bf16x8*)&Xs[w * 16 + l15][q * 8];
#pragma unroll
        for (int ct = 0; ct < 4; ++ct) {
            bf16x8 bfr = *(bf16x8*)&Wsm[ct * 16 + l15][q * 8];
            acc[ct] = __builtin_amdgcn_mfma_f32_16x16x32_bf16(a, bfr, acc[ct], 0, 0, 0);
        }
        __syncthreads();
    }

    if (N0 < 1024) {
        // Q or K path: row-major [bh][row][d]
#pragma unroll
        for (int ct = 0; ct < 4; ++ct) {
            float u0 = isQ ? ub[N0 + ct * 16 + l15] : 0.f;
            float sc = isQ ? 0.125f : 1.0f;
#pragma unroll
            for (int r = 0; r < 4; ++r)
                Ct[w * 16 + q * 4 + r][ct * 16 + l15] = f2bf((acc[ct][r] + u0) * sc);
        }
        __syncthreads();
        int Nh = isQ ? N0 : (N0 - 512);
        unsigned short* out = isQ ? Qb : Kb;
        size_t base = ((size_t)((M0 >> 10) * 8 + (Nh >> 6)) * 1024 + (M0 & 1023)) * 64;
#pragma unroll
        for (int it = 0; it < 2; ++it) {
            int idx = tid + it * 256;
            int row = idx >> 3, sg = idx & 7;
            *(uint4*)(out + base + (size_t)row * 64 + sg * 8) = *(uint4*)&Ct[row][sg * 8];
        }
        if (isQ) {
            // qw = Ct @ wpt^T (per-wave 16-row m-tile), C: row m=q*4+r, col n=l15
            bf16x8 a0 = *(bf16x8*)&Ct[w * 16 + l15][q * 8];
            bf16x8 a1 = *(bf16x8*)&Ct[w * 16 + l15][32 + q * 8];
#pragma unroll
            for (int ct = 0; ct < 4; ++ct) {
                bf16x8 b0 = *(bf16x8*)&wpt_s[ct * 16 + l15][q * 8];
                bf16x8 b1 = *(bf16x8*)&wpt_s[ct * 16 + l15][32 + q * 8];
                f32x4 a = {};
                a = __builtin_amdgcn_mfma_f32_16x16x32_bf16(a0, b0, a, 0, 0, 0);
                a = __builtin_amdgcn_mfma_f32_16x16x32_bf16(a1, b1, a, 0, 0, 0);
#pragma unroll
                for (int r = 0; r < 4; ++r)
                    qwf[w * 16 + q * 4 + r][ct * 16 + l15] = a[r];
            }
            __syncthreads();
            // suffix-sum halves over n, write qsfx
            int n = tid & 63, rg = tid >> 6;
            int nn = n & 31, cbase = n & 32;
            int b = M0 >> 10, bh = b * 8 + h, i0 = M0 & 1023;
            float* qout = qsfx + ((size_t)bh * 1024 + i0) * 64 + n;
#pragma unroll
            for (int rr = 0; rr < 16; ++rr) {
                int row = rg * 16 + rr;
                float s = 0.f;
                for (int c = 31; c >= nn; --c) s += qwf[row][cbase + c];
                qout[(size_t)row * 64] = s;
            }
        }
    } else {
        // V transposed path
#pragma unroll
        for (int ct = 0; ct < 4; ++ct) {
            ushort4 pk;
            pk.x = f2bf(acc[ct][0]); pk.y = f2bf(acc[ct][1]);
            pk.z = f2bf(acc[ct][2]); pk.w = f2bf(acc[ct][3]);
            *(ushort4*)&Ct[ct * 16 + l15][w * 16 + q * 4] = pk;   // [d][j]
        }
        __syncthreads();
        size_t base = ((size_t)((M0 >> 10) * 8 + ((N0 - 1024) >> 6))) * 65536;
        int j0 = M0 & 1023;
#pragma unroll
        for (int it = 0; it < 2; ++it) {
            int idx = tid + it * 256;
            int d = idx >> 3, sg = idx & 7;
            *(uint4*)(Vtb + base + (size_t)d * 1024 + j0 + sg * 8) = *(uint4*)&Ct[d][sg * 8];
        }
    }
}

// ---------------------------------------------------------------------------
// out-projection GEMM: fp32 out [2048][768] = aob[2048][512] @ Wo[768][512]^T + bo
// ---------------------------------------------------------------------------
__global__ __launch_bounds__(256) void gemm_o(
    const unsigned short* __restrict__ X, const unsigned short* __restrict__ W,
    const float* __restrict__ bias, float* __restrict__ out)
{
    __shared__ unsigned short Xs[64][40];
    __shared__ unsigned short Wsm[64][40];
    __shared__ float Ctf[64][72];

    int tid = threadIdx.x;
    int w = tid >> 6, lane = tid & 63, l15 = lane & 15, q = lane >> 4;
    int M0 = blockIdx.y * 64, N0 = blockIdx.x * 64;
    int rs = tid >> 2, seg = tid & 3;

    f32x4 acc[4] = {};
    for (int k0 = 0; k0 < 512; k0 += 32) {
        uint4 xv = *(const uint4*)(X + (size_t)(M0 + rs) * 512 + k0 + seg * 8);
        uint4 wv = *(const uint4*)(W + (size_t)(N0 + rs) * 512 + k0 + seg * 8);
        *(uint4*)&Xs[rs][seg * 8]  = xv;
        *(uint4*)&Wsm[rs][seg * 8] = wv;
        __syncthreads();
        bf16x8 a = *(bf16x8*)&Xs[w * 16 + l15][q * 8];
#pragma unroll
        for (int ct = 0; ct < 4; ++ct) {
            bf16x8 bfr = *(bf16x8*)&Wsm[ct * 16 + l15][q * 8];
            acc[ct] = __builtin_amdgcn_mfma_f32_16x16x32_bf16(a, bfr, acc[ct], 0, 0, 0);
        }
        __syncthreads();
    }
#pragma unroll
    for (int ct = 0; ct < 4; ++ct) {
        float bv = bias[N0 + ct * 16 + l15];
#pragma unroll
        for (int r = 0; r < 4; ++r)
            Ctf[w * 16 + q * 4 + r][ct * 16 + l15] = acc[ct][r] + bv;
    }
    __syncthreads();
#pragma unroll
    for (int it = 0; it < 4; ++it) {
        int idx = tid + it * 256;
        int row = idx >> 4, sg = idx & 15;
        *(float4*)(out + (size_t)(M0 + row) * 768 + N0 + sg * 4) = *(float4*)&Ctf[row][sg * 4];
    }
}

// ---------------------------------------------------------------------------
// MFMA flash attention. Block: 16 query rows, 4 waves = 4 j-quarters.
// No __syncthreads in the K-loop; waves fully independent.
// S^T = K.Q'^T includes the uk term (u folded into Q').
// bias(i,j) = biasT[i][cls[j-i+1023]]  (qr+vr, pre-scaled by 1/8).
// ---------------------------------------------------------------------------
__global__ __launch_bounds__(256, 4) void attn_mfma(
    const unsigned short* __restrict__ Qbf,   // [bh][i][d] bf16 ((q+u)/8)
    const unsigned short* __restrict__ Kbf,   // [bh][j][d] bf16
    const unsigned short* __restrict__ Vt,    // [bh][d][j] bf16
    const float* __restrict__ qsfx,           // [bh][i][64] pre-scaled /8
    const float* __restrict__ wsfx,           // [h][64]  (vsfx-usfx)/8
    const unsigned char* __restrict__ cls_g,
    unsigned short* __restrict__ ao)          // [b*1024+i][h*64+d] bf16
{
    __shared__ float biasT[16 * 99];
    __shared__ unsigned char cls[2048];
    __shared__ unsigned short Pl[4][16][76];
    __shared__ float Obuf[4][64][17];
    __shared__ float lbuf[4][16];

    int tid = threadIdx.x;
    int b = blockIdx.z, h = blockIdx.y, bh = b * 8 + h;
    int i0 = blockIdx.x * 16;
    int w = tid >> 6, lane = tid & 63, l15 = lane & 15, q = lane >> 4;

    for (int idx = tid; idx < 512; idx += 256)
        ((unsigned int*)cls)[idx] = ((const unsigned int*)cls_g)[idx];
    for (int idx = tid; idx < 528; idx += 256) {
        int il = idx / 33, c = idx - il * 33;
        float up = 0.f, sp = 0.f;
        if (c < 32) {
            const float* qs = qsfx + ((size_t)bh * 1024 + i0 + il) * 64;
            const float* vs = wsfx + h * 64;
            up = qs[c] + vs[c];
            sp = qs[32 + c] + vs[32 + c];
        }
        float* bt = biasT + il * 99;
        bt[c]      = up - sp;   // dd < 0
        bt[33 + c] = up;        // dd == 0
        bt[66 + c] = up + sp;   // dd > 0
    }
    __syncthreads();

    int ig = i0 + l15;
    const unsigned short* qrow = Qbf + ((size_t)bh * 1024 + ig) * 64;
    bf16x8 qf0 = *(const bf16x8*)(qrow + q * 8);
    bf16x8 qf1 = *(const bf16x8*)(qrow + 32 + q * 8);
    const unsigned short* Kbase = Kbf + (size_t)bh * 65536;
    const unsigned short* Vbase = Vt  + (size_t)bh * 65536;
    const float* btrow = biasT + l15 * 99;
    int clsoff = 1023 - ig;

    f32x4 Oacc[4] = {};
    float lsum = 0.f;

    for (int jt = 0; jt < 4; ++jt) {
        int jb = w * 256 + jt * 64;
        f32x4 st[4];
#pragma unroll
        for (int ct = 0; ct < 4; ++ct) {
            const unsigned short* krow = Kbase + (size_t)(jb + ct * 16 + l15) * 64;
            bf16x8 ka0 = *(const bf16x8*)(krow + q * 8);
            bf16x8 ka1 = *(const bf16x8*)(krow + 32 + q * 8);
            f32x4 a = {};
            a = __builtin_amdgcn_mfma_f32_16x16x32_bf16(ka0, qf0, a, 0, 0, 0);
            a = __builtin_amdgcn_mfma_f32_16x16x32_bf16(ka1, qf1, a, 0, 0, 0);
            st[ct] = a;
        }
#pragma unroll
        for (int ct = 0; ct < 4; ++ct) {
            int d2b = jb + ct * 16 + q * 4 + clsoff;
            float pv[4];
#pragma unroll
            for (int r = 0; r < 4; ++r) {
                float s = st[ct][r] + btrow[cls[d2b + r]];
                float p = __expf(s);
                lsum += p;
                pv[r] = p;
            }
            ushort4 pk;
            pk.x = f2bf(pv[0]); pk.y = f2bf(pv[1]);
            pk.z = f2bf(pv[2]); pk.w = f2bf(pv[3]);
            *(ushort4*)&Pl[w][l15][ct * 16 + q * 4] = pk;
        }
#pragma unroll
        for (int ks = 0; ks < 2; ++ks) {
            bf16x8 pb = *(const bf16x8*)&Pl[w][l15][ks * 32 + q * 8];
#pragma unroll
            for (int dt = 0; dt < 4; ++dt) {
                bf16x8 va = *(const bf16x8*)(Vbase + (size_t)(dt * 16 + l15) * 1024
                                             + jb + ks * 32 + q * 8);
                Oacc[dt] = __builtin_amdgcn_mfma_f32_16x16x32_bf16(va, pb, Oacc[dt], 0, 0, 0);
            }
        }
    }

    lsum += __shfl_xor(lsum, 16);
    lsum += __shfl_xor(lsum, 32);

#pragma unroll
    for (int dt = 0; dt < 4; ++dt)
#pragma unroll
        for (int r = 0; r < 4; ++r)
            Obuf[w][dt * 16 + q * 4 + r][l15] = Oacc[dt][r];
    if (lane < 16) lbuf[w][l15] = lsum;
    __syncthreads();

    for (int t2 = tid; t2 < 1024; t2 += 256) {
        int il = t2 >> 6, d = t2 & 63;
        float o = Obuf[0][d][il] + Obuf[1][d][il] + Obuf[2][d][il] + Obuf[3][d][il];
        float l = lbuf[0][il] + lbuf[1][il] + lbuf[2][il] + lbuf[3][il];
        ao[((size_t)(b * 1024 + i0 + il)) * 512 + h * 64 + d] = f2bf(o / l);
    }
}

// ---------------------------------------------------------------------------
extern "C" void kernel_launch(void* const* d_in, const int* in_sizes, int n_in,
                              void* d_out, int out_size, void* d_ws, size_t ws_size,
                              hipStream_t stream)
{
    const float* x      = (const float*)d_in[0];
    const float* Wq     = (const float*)d_in[1];
    const float* Wk     = (const float*)d_in[2];
    const float* Wv     = (const float*)d_in[3];
    const float* Wo     = (const float*)d_in[4];
    const float* bo     = (const float*)d_in[5];
    const float* u_bias = (const float*)d_in[6];
    const float* v_bias = (const float*)d_in[7];
    const float* w_pos  = (const float*)d_in[8];
    float* out = (float*)d_out;

    char* ws = (char*)d_ws;
    unsigned short* Xbf  = (unsigned short*)ws;            ws += 3145728;
    unsigned short* Wqkv = (unsigned short*)ws;            ws += 2359296;
    unsigned short* Wob  = (unsigned short*)ws;            ws += 786432;
    unsigned short* Qbf  = (unsigned short*)ws;            ws += 2097152;
    unsigned short* Kbf  = (unsigned short*)ws;            ws += 2097152;
    unsigned short* Vtb  = (unsigned short*)ws;            ws += 2097152;
    unsigned short* aob  = (unsigned short*)ws;            ws += 2097152;
    float*          qsfx = (float*)ws;                     ws += 4194304;
    float*          wsfx = (float*)ws;                     ws += 2048;
    unsigned char*  clsg = (unsigned char*)ws;             ws += 2048;
    unsigned short* wpt  = (unsigned short*)ws;            ws += 65536;

    pack_setup<<<3073, 256, 0, stream>>>(
        (const float4*)x, (const float4*)Wq, (const float4*)Wk,
        (const float4*)Wv, (const float4*)Wo,
        u_bias, v_bias, w_pos,
        (ushort4*)Xbf,
        (ushort4*)Wqkv, (ushort4*)Wqkv + 98304, (ushort4*)Wqkv + 196608,
        (ushort4*)Wob,
        wsfx, clsg, wpt);

    gemm_qkv<<<dim3(24, 32), 256, 0, stream>>>(Xbf, Wqkv, u_bias, wpt,
                                               Qbf, Kbf, Vtb, qsfx);

    attn_mfma<<<dim3(64, 8, 2), 256, 0, stream>>>(
        Qbf, Kbf, Vtb, qsfx, wsfx, clsg, aob);

    gemm_o<<<dim3(12, 32), 256, 0, stream>>>(aob, Wob, bo, out);
}

// Round 5
// 169.638 us; speedup vs baseline: 1.0684x; 1.0684x over previous
//
#include <hip/hip_runtime.h>

#define LSEQ 1024
#define NB   2
#define NH   8
#define DD   64
#define DMOD 768

using bf16x8 = __attribute__((ext_vector_type(8))) short;
using f32x4  = __attribute__((ext_vector_type(4))) float;

__device__ inline unsigned short f2bf(float f) {
    union { float f; unsigned u; } v; v.f = f;
    unsigned r = v.u + 0x7FFFu + ((v.u >> 16) & 1u);
    return (unsigned short)(r >> 16);
}
__device__ inline float bf2f(unsigned short u) {
    union { unsigned u; float f; } v; v.u = ((unsigned)u) << 16;
    return v.f;
}

// ---------------------------------------------------------------------------
// pack x + Wq|Wk|Wv + Wo to bf16; block 3072 does setup:
//   wsfx[h][n] = (suffix(v.w_pos)-suffix(u.w_pos))/8, cls LUT,
//   wpt bf16 [h][n][d] (transpose of w_pos)
// ---------------------------------------------------------------------------
__global__ __launch_bounds__(256) void pack_setup(
    const float4* __restrict__ x,  const float4* __restrict__ wq,
    const float4* __restrict__ wk, const float4* __restrict__ wv,
    const float4* __restrict__ wo,
    const float* __restrict__ u_bias, const float* __restrict__ v_bias,
    const float* __restrict__ w_pos,
    ushort4* __restrict__ xb, ushort4* __restrict__ wqb, ushort4* __restrict__ wkb,
    ushort4* __restrict__ wvb, ushort4* __restrict__ wob,
    float* __restrict__ wsfx, unsigned char* __restrict__ cls_g,
    unsigned short* __restrict__ wpt)
{
    if (blockIdx.x == 3072) {
        __shared__ float w_s[32];
        __shared__ float vw_s[8][64];
        __shared__ float uw_s[8][64];
        __shared__ int cmin_s[1024];
        int tid = threadIdx.x;
        if (tid < 32) {
            float pr = expf(logf(512.5f) / 32.0f);
            w_s[tid] = powf(pr, (float)(tid + 1));
        }
        __syncthreads();
        for (int d = tid; d < 1024; d += 256) {
            float fd = (float)d;
            int cm = 32;
            for (int c = 31; c >= 0; --c) if (fd <= w_s[c]) cm = c;
            cmin_s[d] = cm;
        }
        for (int idx = tid; idx < 512; idx += 256) {
            int hh = idx >> 6, n = idx & 63;
            float vs = 0.f, us = 0.f;
            for (int d = 0; d < 64; ++d) {
                float wp = w_pos[(hh * 64 + d) * 64 + n];
                vs += v_bias[hh * 64 + d] * wp;
                us += u_bias[hh * 64 + d] * wp;
            }
            vw_s[hh][n] = vs;
            uw_s[hh][n] = us;
        }
        __syncthreads();
        for (int idx = tid; idx < 512; idx += 256) {
            int hh = idx >> 6, n = idx & 63;
            float vs = 0.f, us = 0.f;
            if (n < 32) {
                for (int c = n; c < 32; ++c) { vs += vw_s[hh][c]; us += uw_s[hh][c]; }
            } else {
                for (int c = n - 32; c < 32; ++c) { vs += vw_s[hh][32 + c]; us += uw_s[hh][32 + c]; }
            }
            wsfx[idx] = (vs - us) * 0.125f;
        }
        for (int d2 = tid; d2 < 2048; d2 += 256) {
            int dd = d2 - 1023;
            int ad = dd < 0 ? -dd : dd; if (ad > 1023) ad = 1023;
            int t = (dd < 0) ? 0 : ((dd == 0) ? 1 : 2);
            cls_g[d2] = (unsigned char)(t * 33 + cmin_s[ad]);
        }
        // wpt[h][n][d] = bf16(w_pos[h][d][n]) — coalesced reads, scattered writes
        for (int idx = tid; idx < 32768; idx += 256) {
            int hh = idx >> 12, d = (idx >> 6) & 63, n = idx & 63;
            wpt[(hh * 64 + n) * 64 + d] = f2bf(w_pos[(hh * 64 + d) * 64 + n]);
        }
        return;
    }
    int i = blockIdx.x * 256 + threadIdx.x;
    const float4* src; ushort4* dst; int off;
    if (i < 393216)      { src = x;  dst = xb;  off = i; }
    else if (i < 491520) { src = wq; dst = wqb; off = i - 393216; }
    else if (i < 589824) { src = wk; dst = wkb; off = i - 491520; }
    else if (i < 688128) { src = wv; dst = wvb; off = i - 589824; }
    else                 { src = wo; dst = wob; off = i - 688128; }
    float4 v = src[off];
    ushort4 o;
    o.x = f2bf(v.x); o.y = f2bf(v.y); o.z = f2bf(v.z); o.w = f2bf(v.w);
    dst[off] = o;
}

// ---------------------------------------------------------------------------
// fused QKV projection GEMM (R3 version): [2048x768] @ [1536x768]^T
//   n <  512: Q' = (q + u_bias)/8 -> bf16 [bh][i][d]
//   n < 1024: K  -> bf16 [bh][j][d]
//   else    : V  -> bf16 transposed [bh][d][j]
// ---------------------------------------------------------------------------
__global__ __launch_bounds__(256) void gemm_qkv(
    const unsigned short* __restrict__ X, const unsigned short* __restrict__ W,
    const float* __restrict__ ub,
    unsigned short* __restrict__ Qb, unsigned short* __restrict__ Kb,
    unsigned short* __restrict__ Vtb)
{
    __shared__ unsigned short Xs[64][40];
    __shared__ unsigned short Wsm[64][40];
    __shared__ unsigned short Ct[64][72];

    int tid = threadIdx.x;
    int w = tid >> 6, lane = tid & 63, l15 = lane & 15, q = lane >> 4;
    int M0 = blockIdx.y * 64, N0 = blockIdx.x * 64;
    int rs = tid >> 2, seg = tid & 3;

    f32x4 acc[4] = {};
    for (int k0 = 0; k0 < 768; k0 += 32) {
        uint4 xv = *(const uint4*)(X + (size_t)(M0 + rs) * 768 + k0 + seg * 8);
        uint4 wv = *(const uint4*)(W + (size_t)(N0 + rs) * 768 + k0 + seg * 8);
        *(uint4*)&Xs[rs][seg * 8]  = xv;
        *(uint4*)&Wsm[rs][seg * 8] = wv;
        __syncthreads();
        bf16x8 a = *(bf16x8*)&Xs[w * 16 + l15][q * 8];
#pragma unroll
        for (int ct = 0; ct < 4; ++ct) {
            bf16x8 bfr = *(bf16x8*)&Wsm[ct * 16 + l15][q * 8];
            acc[ct] = __builtin_amdgcn_mfma_f32_16x16x32_bf16(a, bfr, acc[ct], 0, 0, 0);
        }
        __syncthreads();
    }

    if (N0 < 1024) {
        int isQ = (N0 < 512);
#pragma unroll
        for (int ct = 0; ct < 4; ++ct) {
            float u0 = isQ ? ub[N0 + ct * 16 + l15] : 0.f;
            float sc = isQ ? 0.125f : 1.0f;
#pragma unroll
            for (int r = 0; r < 4; ++r)
                Ct[w * 16 + q * 4 + r][ct * 16 + l15] = f2bf((acc[ct][r] + u0) * sc);
        }
        __syncthreads();
        int Nh = isQ ? N0 : (N0 - 512);
        unsigned short* out = isQ ? Qb : Kb;
        size_t base = ((size_t)((M0 >> 10) * 8 + (Nh >> 6)) * 1024 + (M0 & 1023)) * 64;
#pragma unroll
        for (int it = 0; it < 2; ++it) {
            int idx = tid + it * 256;
            int row = idx >> 3, sg = idx & 7;
            *(uint4*)(out + base + (size_t)row * 64 + sg * 8) = *(uint4*)&Ct[row][sg * 8];
        }
    } else {
#pragma unroll
        for (int ct = 0; ct < 4; ++ct) {
            ushort4 pk;
            pk.x = f2bf(acc[ct][0]); pk.y = f2bf(acc[ct][1]);
            pk.z = f2bf(acc[ct][2]); pk.w = f2bf(acc[ct][3]);
            *(ushort4*)&Ct[ct * 16 + l15][w * 16 + q * 4] = pk;   // [d][j]
        }
        __syncthreads();
        size_t base = ((size_t)((M0 >> 10) * 8 + ((N0 - 1024) >> 6))) * 65536;
        int j0 = M0 & 1023;
#pragma unroll
        for (int it = 0; it < 2; ++it) {
            int idx = tid + it * 256;
            int d = idx >> 3, sg = idx & 7;
            *(uint4*)(Vtb + base + (size_t)d * 1024 + j0 + sg * 8) = *(uint4*)&Ct[d][sg * 8];
        }
    }
}

// ---------------------------------------------------------------------------
// out-projection GEMM: fp32 out [2048][768] = aob[2048][512] @ Wo[768][512]^T + bo
// ---------------------------------------------------------------------------
__global__ __launch_bounds__(256) void gemm_o(
    const unsigned short* __restrict__ X, const unsigned short* __restrict__ W,
    const float* __restrict__ bias, float* __restrict__ out)
{
    __shared__ unsigned short Xs[64][40];
    __shared__ unsigned short Wsm[64][40];
    __shared__ float Ctf[64][72];

    int tid = threadIdx.x;
    int w = tid >> 6, lane = tid & 63, l15 = lane & 15, q = lane >> 4;
    int M0 = blockIdx.y * 64, N0 = blockIdx.x * 64;
    int rs = tid >> 2, seg = tid & 3;

    f32x4 acc[4] = {};
    for (int k0 = 0; k0 < 512; k0 += 32) {
        uint4 xv = *(const uint4*)(X + (size_t)(M0 + rs) * 512 + k0 + seg * 8);
        uint4 wv = *(const uint4*)(W + (size_t)(N0 + rs) * 512 + k0 + seg * 8);
        *(uint4*)&Xs[rs][seg * 8]  = xv;
        *(uint4*)&Wsm[rs][seg * 8] = wv;
        __syncthreads();
        bf16x8 a = *(bf16x8*)&Xs[w * 16 + l15][q * 8];
#pragma unroll
        for (int ct = 0; ct < 4; ++ct) {
            bf16x8 bfr = *(bf16x8*)&Wsm[ct * 16 + l15][q * 8];
            acc[ct] = __builtin_amdgcn_mfma_f32_16x16x32_bf16(a, bfr, acc[ct], 0, 0, 0);
        }
        __syncthreads();
    }
#pragma unroll
    for (int ct = 0; ct < 4; ++ct) {
        float bv = bias[N0 + ct * 16 + l15];
#pragma unroll
        for (int r = 0; r < 4; ++r)
            Ctf[w * 16 + q * 4 + r][ct * 16 + l15] = acc[ct][r] + bv;
    }
    __syncthreads();
#pragma unroll
    for (int it = 0; it < 4; ++it) {
        int idx = tid + it * 256;
        int row = idx >> 4, sg = idx & 15;
        *(float4*)(out + (size_t)(M0 + row) * 768 + N0 + sg * 4) = *(float4*)&Ctf[row][sg * 4];
    }
}

// ---------------------------------------------------------------------------
// MFMA flash attention with fused qr-bias computation.
// Preamble: qw = Q'_tile @ wpt[h]^T (2 MFMA/wave), broadcast suffix-scan,
//           biasT built in LDS. No qsfx global round-trip.
// K-loop: 4 waves = 4 j-quarters, no barriers, waves independent.
// ---------------------------------------------------------------------------
__global__ __launch_bounds__(256, 4) void attn_mfma(
    const unsigned short* __restrict__ Qbf,   // [bh][i][d] bf16 ((q+u)/8)
    const unsigned short* __restrict__ Kbf,   // [bh][j][d] bf16
    const unsigned short* __restrict__ Vt,    // [bh][d][j] bf16
    const unsigned short* __restrict__ wpt,   // [h][n][d] bf16
    const float* __restrict__ wsfx,           // [h][64]  (vsfx-usfx)/8
    const unsigned char* __restrict__ cls_g,
    unsigned short* __restrict__ ao)          // [b*1024+i][h*64+d] bf16
{
    __shared__ float biasT[16 * 99];
    __shared__ unsigned char cls[2048];
    __shared__ unsigned short Pl[4][16][76];
    union Ovl {
        struct { unsigned short wptS[64][68]; float qwL[16][68]; } pre;
        struct { float Obuf[4][64][17]; float lbuf[4][16]; } post;
    };
    __shared__ Ovl ovl;

    int tid = threadIdx.x;
    int b = blockIdx.z, h = blockIdx.y, bh = b * 8 + h;
    int i0 = blockIdx.x * 16;
    int w = tid >> 6, lane = tid & 63, l15 = lane & 15, q = lane >> 4;

    for (int idx = tid; idx < 512; idx += 256)
        ((unsigned int*)cls)[idx] = ((const unsigned int*)cls_g)[idx];
    // stage wpt[h] into padded LDS (row stride 68 shorts -> no 16-way conflicts)
    {
        const unsigned short* wsrc = wpt + h * 4096;
#pragma unroll
        for (int it = 0; it < 2; ++it) {
            int idx = tid + it * 256;
            int n = idx >> 3, seg = idx & 7;
            *(uint4*)&ovl.pre.wptS[n][seg * 8] = *(const uint4*)(wsrc + n * 64 + seg * 8);
        }
    }

    int ig = i0 + l15;
    const unsigned short* qrow = Qbf + ((size_t)bh * 1024 + ig) * 64;
    bf16x8 qf0 = *(const bf16x8*)(qrow + q * 8);
    bf16x8 qf1 = *(const bf16x8*)(qrow + 32 + q * 8);
    __syncthreads();

    // qw MFMA: wave w covers n = w*16 .. w*16+15
    {
        bf16x8 b0 = *(bf16x8*)&ovl.pre.wptS[w * 16 + l15][q * 8];
        bf16x8 b1 = *(bf16x8*)&ovl.pre.wptS[w * 16 + l15][32 + q * 8];
        f32x4 a = {};
        a = __builtin_amdgcn_mfma_f32_16x16x32_bf16(qf0, b0, a, 0, 0, 0);
        a = __builtin_amdgcn_mfma_f32_16x16x32_bf16(qf1, b1, a, 0, 0, 0);
#pragma unroll
        for (int r = 0; r < 4; ++r)
            ovl.pre.qwL[q * 4 + r][w * 16 + l15] = a[r];
    }
    __syncthreads();

    // suffix-scan halves (fixed 32 iters, broadcast reads) + add wsfx, in-place.
    // Rows partitioned by wave (wave w handles il = w + it*4), wave-synchronous.
    const float* wsh = wsfx + h * 64;
#pragma unroll
    for (int it = 0; it < 4; ++it) {
        int idx = tid + it * 256;
        int il = idx >> 6, n = idx & 63, nn = n & 31, cb = n & 32;
        float run = 0.f, s = 0.f;
#pragma unroll
        for (int c = 31; c >= 0; --c) {
            run += ovl.pre.qwL[il][cb + c];
            if (c == nn) s = run;
        }
        ovl.pre.qwL[il][n] = s + wsh[n];
    }
    __syncthreads();

    for (int idx = tid; idx < 528; idx += 256) {
        int il = idx / 33, c = idx - il * 33;
        float up = 0.f, sp = 0.f;
        if (c < 32) {
            up = ovl.pre.qwL[il][c];
            sp = ovl.pre.qwL[il][32 + c];
        }
        float* bt = biasT + il * 99;
        bt[c]      = up - sp;   // dd < 0
        bt[33 + c] = up;        // dd == 0
        bt[66 + c] = up + sp;   // dd > 0
    }
    __syncthreads();

    const unsigned short* Kbase = Kbf + (size_t)bh * 65536;
    const unsigned short* Vbase = Vt  + (size_t)bh * 65536;
    const float* btrow = biasT + l15 * 99;
    int clsoff = 1023 - ig;

    f32x4 Oacc[4] = {};
    float lsum = 0.f;

    for (int jt = 0; jt < 4; ++jt) {
        int jb = w * 256 + jt * 64;
        f32x4 st[4];
#pragma unroll
        for (int ct = 0; ct < 4; ++ct) {
            const unsigned short* krow = Kbase + (size_t)(jb + ct * 16 + l15) * 64;
            bf16x8 ka0 = *(const bf16x8*)(krow + q * 8);
            bf16x8 ka1 = *(const bf16x8*)(krow + 32 + q * 8);
            f32x4 a = {};
            a = __builtin_amdgcn_mfma_f32_16x16x32_bf16(ka0, qf0, a, 0, 0, 0);
            a = __builtin_amdgcn_mfma_f32_16x16x32_bf16(ka1, qf1, a, 0, 0, 0);
            st[ct] = a;
        }
#pragma unroll
        for (int ct = 0; ct < 4; ++ct) {
            int d2b = jb + ct * 16 + q * 4 + clsoff;
            float pv[4];
#pragma unroll
            for (int r = 0; r < 4; ++r) {
                float s = st[ct][r] + btrow[cls[d2b + r]];
                float p = __expf(s);
                lsum += p;
                pv[r] = p;
            }
            ushort4 pk;
            pk.x = f2bf(pv[0]); pk.y = f2bf(pv[1]);
            pk.z = f2bf(pv[2]); pk.w = f2bf(pv[3]);
            *(ushort4*)&Pl[w][l15][ct * 16 + q * 4] = pk;
        }
#pragma unroll
        for (int ks = 0; ks < 2; ++ks) {
            bf16x8 pb = *(const bf16x8*)&Pl[w][l15][ks * 32 + q * 8];
#pragma unroll
            for (int dt = 0; dt < 4; ++dt) {
                bf16x8 va = *(const bf16x8*)(Vbase + (size_t)(dt * 16 + l15) * 1024
                                             + jb + ks * 32 + q * 8);
                Oacc[dt] = __builtin_amdgcn_mfma_f32_16x16x32_bf16(va, pb, Oacc[dt], 0, 0, 0);
            }
        }
    }

    lsum += __shfl_xor(lsum, 16);
    lsum += __shfl_xor(lsum, 32);

    __syncthreads();   // all preamble/K-loop reads done before overlay reuse
#pragma unroll
    for (int dt = 0; dt < 4; ++dt)
#pragma unroll
        for (int r = 0; r < 4; ++r)
            ovl.post.Obuf[w][dt * 16 + q * 4 + r][l15] = Oacc[dt][r];
    if (lane < 16) ovl.post.lbuf[w][l15] = lsum;
    __syncthreads();

    for (int t2 = tid; t2 < 1024; t2 += 256) {
        int il = t2 >> 6, d = t2 & 63;
        float o = ovl.post.Obuf[0][d][il] + ovl.post.Obuf[1][d][il]
                + ovl.post.Obuf[2][d][il] + ovl.post.Obuf[3][d][il];
        float l = ovl.post.lbuf[0][il] + ovl.post.lbuf[1][il]
                + ovl.post.lbuf[2][il] + ovl.post.lbuf[3][il];
        ao[((size_t)(b * 1024 + i0 + il)) * 512 + h * 64 + d] = f2bf(o / l);
    }
}

// ---------------------------------------------------------------------------
extern "C" void kernel_launch(void* const* d_in, const int* in_sizes, int n_in,
                              void* d_out, int out_size, void* d_ws, size_t ws_size,
                              hipStream_t stream)
{
    const float* x      = (const float*)d_in[0];
    const float* Wq     = (const float*)d_in[1];
    const float* Wk     = (const float*)d_in[2];
    const float* Wv     = (const float*)d_in[3];
    const float* Wo     = (const float*)d_in[4];
    const float* bo     = (const float*)d_in[5];
    const float* u_bias = (const float*)d_in[6];
    const float* v_bias = (const float*)d_in[7];
    const float* w_pos  = (const float*)d_in[8];
    float* out = (float*)d_out;

    char* ws = (char*)d_ws;
    unsigned short* Xbf  = (unsigned short*)ws;            ws += 3145728;
    unsigned short* Wqkv = (unsigned short*)ws;            ws += 2359296;
    unsigned short* Wob  = (unsigned short*)ws;            ws += 786432;
    unsigned short* Qbf  = (unsigned short*)ws;            ws += 2097152;
    unsigned short* Kbf  = (unsigned short*)ws;            ws += 2097152;
    unsigned short* Vtb  = (unsigned short*)ws;            ws += 2097152;
    unsigned short* aob  = (unsigned short*)ws;            ws += 2097152;
    float*          wsfx = (float*)ws;                     ws += 2048;
    unsigned char*  clsg = (unsigned char*)ws;             ws += 2048;
    unsigned short* wpt  = (unsigned short*)ws;            ws += 65536;

    pack_setup<<<3073, 256, 0, stream>>>(
        (const float4*)x, (const float4*)Wq, (const float4*)Wk,
        (const float4*)Wv, (const float4*)Wo,
        u_bias, v_bias, w_pos,
        (ushort4*)Xbf,
        (ushort4*)Wqkv, (ushort4*)Wqkv + 98304, (ushort4*)Wqkv + 196608,
        (ushort4*)Wob,
        wsfx, clsg, wpt);

    gemm_qkv<<<dim3(24, 32), 256, 0, stream>>>(Xbf, Wqkv, u_bias, Qbf, Kbf, Vtb);

    attn_mfma<<<dim3(64, 8, 2), 256, 0, stream>>>(
        Qbf, Kbf, Vtb, wpt, wsfx, clsg, aob);

    gemm_o<<<dim3(12, 32), 256, 0, stream>>>(aob, Wob, bo, out);
}

// Round 6
// 136.967 us; speedup vs baseline: 1.3232x; 1.2385x over previous
//
#include <hip/hip_runtime.h>

#define LSEQ 1024
#define NB   2
#define NH   8
#define DD   64
#define DMOD 768

using bf16x8 = __attribute__((ext_vector_type(8))) short;
using f32x4  = __attribute__((ext_vector_type(4))) float;

__device__ inline unsigned short f2bf(float f) {
    union { float f; unsigned u; } v; v.f = f;
    unsigned r = v.u + 0x7FFFu + ((v.u >> 16) & 1u);
    return (unsigned short)(r >> 16);
}

// ---------------------------------------------------------------------------
// blocks 0..3071: pack x + Wq|Wk|Wv + Wo to bf16 (streaming)
// block  3072   : cls LUT (2048 u8)
// blocks 3073..3080: per-head wsfx[h][n] = (suffix(v.w_pos)-suffix(u.w_pos))/8
// ---------------------------------------------------------------------------
__global__ __launch_bounds__(256) void pack_setup(
    const float4* __restrict__ x,  const float4* __restrict__ wq,
    const float4* __restrict__ wk, const float4* __restrict__ wv,
    const float4* __restrict__ wo,
    const float* __restrict__ u_bias, const float* __restrict__ v_bias,
    const float* __restrict__ w_pos,
    ushort4* __restrict__ xb, ushort4* __restrict__ wqb, ushort4* __restrict__ wkb,
    ushort4* __restrict__ wvb, ushort4* __restrict__ wob,
    float* __restrict__ wsfx, unsigned char* __restrict__ cls_g)
{
    int tid = threadIdx.x;
    if (blockIdx.x >= 3072) {
        int sb = blockIdx.x - 3072;
        if (sb == 0) {
            // cls LUT
            __shared__ float w_s[32];
            __shared__ int cmin_s[1024];
            if (tid < 32) {
                float pr = expf(logf(512.5f) / 32.0f);
                w_s[tid] = powf(pr, (float)(tid + 1));
            }
            __syncthreads();
            for (int d = tid; d < 1024; d += 256) {
                float fd = (float)d;
                int cm = 32;
                for (int c = 31; c >= 0; --c) if (fd <= w_s[c]) cm = c;
                cmin_s[d] = cm;
            }
            __syncthreads();
            for (int d2 = tid; d2 < 2048; d2 += 256) {
                int dd = d2 - 1023;
                int ad = dd < 0 ? -dd : dd; if (ad > 1023) ad = 1023;
                int t = (dd < 0) ? 0 : ((dd == 0) ? 1 : 2);
                cls_g[d2] = (unsigned char)(t * 33 + cmin_s[ad]);
            }
        } else {
            // per-head wsfx
            int h = sb - 1;
            __shared__ float vred[4][64];
            __shared__ float ured[4][64];
            __shared__ float wd[64];
            int n = tid & 63, g = tid >> 6;
            float vs = 0.f, us = 0.f;
#pragma unroll
            for (int k = 0; k < 16; ++k) {
                int d = g * 16 + k;
                float wp = w_pos[(h * 64 + d) * 64 + n];
                vs += v_bias[h * 64 + d] * wp;
                us += u_bias[h * 64 + d] * wp;
            }
            vred[g][n] = vs; ured[g][n] = us;
            __syncthreads();
            if (tid < 64) {
                float v4 = vred[0][tid] + vred[1][tid] + vred[2][tid] + vred[3][tid];
                float u4 = ured[0][tid] + ured[1][tid] + ured[2][tid] + ured[3][tid];
                wd[tid] = v4 - u4;
            }
            __syncthreads();
            if (tid < 64) {
                int nn = tid & 31, cb = tid & 32;
                float s = 0.f;
                for (int c = 31; c >= nn; --c) s += wd[cb + c];
                wsfx[h * 64 + tid] = s * 0.125f;
            }
        }
        return;
    }
    int i = blockIdx.x * 256 + tid;
    const float4* src; ushort4* dst; int off;
    if (i < 393216)      { src = x;  dst = xb;  off = i; }
    else if (i < 491520) { src = wq; dst = wqb; off = i - 393216; }
    else if (i < 589824) { src = wk; dst = wkb; off = i - 491520; }
    else if (i < 688128) { src = wv; dst = wvb; off = i - 589824; }
    else                 { src = wo; dst = wob; off = i - 688128; }
    float4 v = src[off];
    ushort4 o;
    o.x = f2bf(v.x); o.y = f2bf(v.y); o.z = f2bf(v.z); o.w = f2bf(v.w);
    dst[off] = o;
}

// ---------------------------------------------------------------------------
// fused QKV projection GEMM: [2048x768] @ [1536x768]^T, 64x64 tile, 4 waves
//   n <  512: Q' = (q + u_bias)/8 -> bf16 [bh][i][d]
//   n < 1024: K  -> bf16 [bh][j][d]
//   else    : V  -> bf16 transposed [bh][d][j]
// ---------------------------------------------------------------------------
__global__ __launch_bounds__(256) void gemm_qkv(
    const unsigned short* __restrict__ X, const unsigned short* __restrict__ W,
    const float* __restrict__ ub,
    unsigned short* __restrict__ Qb, unsigned short* __restrict__ Kb,
    unsigned short* __restrict__ Vtb)
{
    __shared__ unsigned short Xs[64][40];
    __shared__ unsigned short Wsm[64][40];
    __shared__ unsigned short Ct[64][72];

    int tid = threadIdx.x;
    int w = tid >> 6, lane = tid & 63, l15 = lane & 15, q = lane >> 4;
    int M0 = blockIdx.y * 64, N0 = blockIdx.x * 64;
    int rs = tid >> 2, seg = tid & 3;

    f32x4 acc[4] = {};
    for (int k0 = 0; k0 < 768; k0 += 32) {
        uint4 xv = *(const uint4*)(X + (size_t)(M0 + rs) * 768 + k0 + seg * 8);
        uint4 wv = *(const uint4*)(W + (size_t)(N0 + rs) * 768 + k0 + seg * 8);
        *(uint4*)&Xs[rs][seg * 8]  = xv;
        *(uint4*)&Wsm[rs][seg * 8] = wv;
        __syncthreads();
        bf16x8 a = *(bf16x8*)&Xs[w * 16 + l15][q * 8];
#pragma unroll
        for (int ct = 0; ct < 4; ++ct) {
            bf16x8 bfr = *(bf16x8*)&Wsm[ct * 16 + l15][q * 8];
            acc[ct] = __builtin_amdgcn_mfma_f32_16x16x32_bf16(a, bfr, acc[ct], 0, 0, 0);
        }
        __syncthreads();
    }

    if (N0 < 1024) {
        int isQ = (N0 < 512);
#pragma unroll
        for (int ct = 0; ct < 4; ++ct) {
            float u0 = isQ ? ub[N0 + ct * 16 + l15] : 0.f;
            float sc = isQ ? 0.125f : 1.0f;
#pragma unroll
            for (int r = 0; r < 4; ++r)
                Ct[w * 16 + q * 4 + r][ct * 16 + l15] = f2bf((acc[ct][r] + u0) * sc);
        }
        __syncthreads();
        int Nh = isQ ? N0 : (N0 - 512);
        unsigned short* out = isQ ? Qb : Kb;
        size_t base = ((size_t)((M0 >> 10) * 8 + (Nh >> 6)) * 1024 + (M0 & 1023)) * 64;
#pragma unroll
        for (int it = 0; it < 2; ++it) {
            int idx = tid + it * 256;
            int row = idx >> 3, sg = idx & 7;
            *(uint4*)(out + base + (size_t)row * 64 + sg * 8) = *(uint4*)&Ct[row][sg * 8];
        }
    } else {
#pragma unroll
        for (int ct = 0; ct < 4; ++ct) {
            ushort4 pk;
            pk.x = f2bf(acc[ct][0]); pk.y = f2bf(acc[ct][1]);
            pk.z = f2bf(acc[ct][2]); pk.w = f2bf(acc[ct][3]);
            *(ushort4*)&Ct[ct * 16 + l15][w * 16 + q * 4] = pk;   // [d][j]
        }
        __syncthreads();
        size_t base = ((size_t)((M0 >> 10) * 8 + ((N0 - 1024) >> 6))) * 65536;
        int j0 = M0 & 1023;
#pragma unroll
        for (int it = 0; it < 2; ++it) {
            int idx = tid + it * 256;
            int d = idx >> 3, sg = idx & 7;
            *(uint4*)(Vtb + base + (size_t)d * 1024 + j0 + sg * 8) = *(uint4*)&Ct[d][sg * 8];
        }
    }
}

// ---------------------------------------------------------------------------
// out-projection GEMM: fp32 out [2048][768] = aob[2048][512] @ Wo[768][512]^T + bo
// ---------------------------------------------------------------------------
__global__ __launch_bounds__(256) void gemm_o(
    const unsigned short* __restrict__ X, const unsigned short* __restrict__ W,
    const float* __restrict__ bias, float* __restrict__ out)
{
    __shared__ unsigned short Xs[64][40];
    __shared__ unsigned short Wsm[64][40];
    __shared__ float Ctf[64][72];

    int tid = threadIdx.x;
    int w = tid >> 6, lane = tid & 63, l15 = lane & 15, q = lane >> 4;
    int M0 = blockIdx.y * 64, N0 = blockIdx.x * 64;
    int rs = tid >> 2, seg = tid & 3;

    f32x4 acc[4] = {};
    for (int k0 = 0; k0 < 512; k0 += 32) {
        uint4 xv = *(const uint4*)(X + (size_t)(M0 + rs) * 512 + k0 + seg * 8);
        uint4 wv = *(const uint4*)(W + (size_t)(N0 + rs) * 512 + k0 + seg * 8);
        *(uint4*)&Xs[rs][seg * 8]  = xv;
        *(uint4*)&Wsm[rs][seg * 8] = wv;
        __syncthreads();
        bf16x8 a = *(bf16x8*)&Xs[w * 16 + l15][q * 8];
#pragma unroll
        for (int ct = 0; ct < 4; ++ct) {
            bf16x8 bfr = *(bf16x8*)&Wsm[ct * 16 + l15][q * 8];
            acc[ct] = __builtin_amdgcn_mfma_f32_16x16x32_bf16(a, bfr, acc[ct], 0, 0, 0);
        }
        __syncthreads();
    }
#pragma unroll
    for (int ct = 0; ct < 4; ++ct) {
        float bv = bias[N0 + ct * 16 + l15];
#pragma unroll
        for (int r = 0; r < 4; ++r)
            Ctf[w * 16 + q * 4 + r][ct * 16 + l15] = acc[ct][r] + bv;
    }
    __syncthreads();
#pragma unroll
    for (int it = 0; it < 4; ++it) {
        int idx = tid + it * 256;
        int row = idx >> 4, sg = idx & 15;
        *(float4*)(out + (size_t)(M0 + row) * 768 + N0 + sg * 4) = *(float4*)&Ctf[row][sg * 4];
    }
}

// ---------------------------------------------------------------------------
// MFMA flash attention with fused qr-bias computation.
// Preamble: stage w_pos[h] fp32->bf16 transposed into LDS; qw = Q'@w_pos^T
//           (2 MFMA/wave); broadcast suffix-scan; biasT in LDS.
// K-loop: 4 waves = 4 j-quarters, no barriers, waves independent.
// ---------------------------------------------------------------------------
__global__ __launch_bounds__(256, 4) void attn_mfma(
    const unsigned short* __restrict__ Qbf,   // [bh][i][d] bf16 ((q+u)/8)
    const unsigned short* __restrict__ Kbf,   // [bh][j][d] bf16
    const unsigned short* __restrict__ Vt,    // [bh][d][j] bf16
    const float* __restrict__ w_pos,          // [h][d][n] fp32
    const float* __restrict__ wsfx,           // [h][64]  (vsfx-usfx)/8
    const unsigned char* __restrict__ cls_g,
    unsigned short* __restrict__ ao)          // [b*1024+i][h*64+d] bf16
{
    __shared__ float biasT[16 * 99];
    __shared__ unsigned char cls[2048];
    __shared__ unsigned short Pl[4][16][76];
    union Ovl {
        struct { unsigned short wptS[64][68]; float qwL[16][68]; } pre;
        struct { float Obuf[4][64][17]; float lbuf[4][16]; } post;
    };
    __shared__ Ovl ovl;

    int tid = threadIdx.x;
    int b = blockIdx.z, h = blockIdx.y, bh = b * 8 + h;
    int i0 = blockIdx.x * 16;
    int w = tid >> 6, lane = tid & 63, l15 = lane & 15, q = lane >> 4;

    for (int idx = tid; idx < 512; idx += 256)
        ((unsigned int*)cls)[idx] = ((const unsigned int*)cls_g)[idx];
    // stage w_pos[h] (fp32 [d][n]) -> bf16 transposed wptS[n][d], padded rows
    {
        const float4* wsrc = (const float4*)(w_pos + h * 4096);
#pragma unroll
        for (int it = 0; it < 4; ++it) {
            int f = tid + it * 256;          // float4 index, 0..1023
            float4 wv = wsrc[f];
            int d = f >> 4, n4 = (f & 15) * 4;
            ovl.pre.wptS[n4 + 0][d] = f2bf(wv.x);
            ovl.pre.wptS[n4 + 1][d] = f2bf(wv.y);
            ovl.pre.wptS[n4 + 2][d] = f2bf(wv.z);
            ovl.pre.wptS[n4 + 3][d] = f2bf(wv.w);
        }
    }

    int ig = i0 + l15;
    const unsigned short* qrow = Qbf + ((size_t)bh * 1024 + ig) * 64;
    bf16x8 qf0 = *(const bf16x8*)(qrow + q * 8);
    bf16x8 qf1 = *(const bf16x8*)(qrow + 32 + q * 8);
    __syncthreads();

    // qw MFMA: wave w covers n = w*16 .. w*16+15
    {
        bf16x8 b0 = *(bf16x8*)&ovl.pre.wptS[w * 16 + l15][q * 8];
        bf16x8 b1 = *(bf16x8*)&ovl.pre.wptS[w * 16 + l15][32 + q * 8];
        f32x4 a = {};
        a = __builtin_amdgcn_mfma_f32_16x16x32_bf16(qf0, b0, a, 0, 0, 0);
        a = __builtin_amdgcn_mfma_f32_16x16x32_bf16(qf1, b1, a, 0, 0, 0);
#pragma unroll
        for (int r = 0; r < 4; ++r)
            ovl.pre.qwL[q * 4 + r][w * 16 + l15] = a[r];
    }
    __syncthreads();

    // suffix-scan halves (fixed 32 iters, broadcast reads) + add wsfx, in-place
    const float* wsh = wsfx + h * 64;
#pragma unroll
    for (int it = 0; it < 4; ++it) {
        int idx = tid + it * 256;
        int il = idx >> 6, n = idx & 63, nn = n & 31, cb = n & 32;
        float run = 0.f, s = 0.f;
#pragma unroll
        for (int c = 31; c >= 0; --c) {
            run += ovl.pre.qwL[il][cb + c];
            if (c == nn) s = run;
        }
        ovl.pre.qwL[il][n] = s + wsh[n];
    }
    __syncthreads();

    for (int idx = tid; idx < 528; idx += 256) {
        int il = idx / 33, c = idx - il * 33;
        float up = 0.f, sp = 0.f;
        if (c < 32) {
            up = ovl.pre.qwL[il][c];
            sp = ovl.pre.qwL[il][32 + c];
        }
        float* bt = biasT + il * 99;
        bt[c]      = up - sp;   // dd < 0
        bt[33 + c] = up;        // dd == 0
        bt[66 + c] = up + sp;   // dd > 0
    }
    __syncthreads();

    const unsigned short* Kbase = Kbf + (size_t)bh * 65536;
    const unsigned short* Vbase = Vt  + (size_t)bh * 65536;
    const float* btrow = biasT + l15 * 99;
    int clsoff = 1023 - ig;

    f32x4 Oacc[4] = {};
    float lsum = 0.f;

    for (int jt = 0; jt < 4; ++jt) {
        int jb = w * 256 + jt * 64;
        f32x4 st[4];
#pragma unroll
        for (int ct = 0; ct < 4; ++ct) {
            const unsigned short* krow = Kbase + (size_t)(jb + ct * 16 + l15) * 64;
            bf16x8 ka0 = *(const bf16x8*)(krow + q * 8);
            bf16x8 ka1 = *(const bf16x8*)(krow + 32 + q * 8);
            f32x4 a = {};
            a = __builtin_amdgcn_mfma_f32_16x16x32_bf16(ka0, qf0, a, 0, 0, 0);
            a = __builtin_amdgcn_mfma_f32_16x16x32_bf16(ka1, qf1, a, 0, 0, 0);
            st[ct] = a;
        }
#pragma unroll
        for (int ct = 0; ct < 4; ++ct) {
            int d2b = jb + ct * 16 + q * 4 + clsoff;
            float pv[4];
#pragma unroll
            for (int r = 0; r < 4; ++r) {
                float s = st[ct][r] + btrow[cls[d2b + r]];
                float p = __expf(s);
                lsum += p;
                pv[r] = p;
            }
            ushort4 pk;
            pk.x = f2bf(pv[0]); pk.y = f2bf(pv[1]);
            pk.z = f2bf(pv[2]); pk.w = f2bf(pv[3]);
            *(ushort4*)&Pl[w][l15][ct * 16 + q * 4] = pk;
        }
#pragma unroll
        for (int ks = 0; ks < 2; ++ks) {
            bf16x8 pb = *(const bf16x8*)&Pl[w][l15][ks * 32 + q * 8];
#pragma unroll
            for (int dt = 0; dt < 4; ++dt) {
                bf16x8 va = *(const bf16x8*)(Vbase + (size_t)(dt * 16 + l15) * 1024
                                             + jb + ks * 32 + q * 8);
                Oacc[dt] = __builtin_amdgcn_mfma_f32_16x16x32_bf16(va, pb, Oacc[dt], 0, 0, 0);
            }
        }
    }

    lsum += __shfl_xor(lsum, 16);
    lsum += __shfl_xor(lsum, 32);

    __syncthreads();   // all preamble/K-loop reads done before overlay reuse
#pragma unroll
    for (int dt = 0; dt < 4; ++dt)
#pragma unroll
        for (int r = 0; r < 4; ++r)
            ovl.post.Obuf[w][dt * 16 + q * 4 + r][l15] = Oacc[dt][r];
    if (lane < 16) ovl.post.lbuf[w][l15] = lsum;
    __syncthreads();

    for (int t2 = tid; t2 < 1024; t2 += 256) {
        int il = t2 >> 6, d = t2 & 63;
        float o = ovl.post.Obuf[0][d][il] + ovl.post.Obuf[1][d][il]
                + ovl.post.Obuf[2][d][il] + ovl.post.Obuf[3][d][il];
        float l = ovl.post.lbuf[0][il] + ovl.post.lbuf[1][il]
                + ovl.post.lbuf[2][il] + ovl.post.lbuf[3][il];
        ao[((size_t)(b * 1024 + i0 + il)) * 512 + h * 64 + d] = f2bf(o / l);
    }
}

// ---------------------------------------------------------------------------
extern "C" void kernel_launch(void* const* d_in, const int* in_sizes, int n_in,
                              void* d_out, int out_size, void* d_ws, size_t ws_size,
                              hipStream_t stream)
{
    const float* x      = (const float*)d_in[0];
    const float* Wq     = (const float*)d_in[1];
    const float* Wk     = (const float*)d_in[2];
    const float* Wv     = (const float*)d_in[3];
    const float* Wo     = (const float*)d_in[4];
    const float* bo     = (const float*)d_in[5];
    const float* u_bias = (const float*)d_in[6];
    const float* v_bias = (const float*)d_in[7];
    const float* w_pos  = (const float*)d_in[8];
    float* out = (float*)d_out;

    char* ws = (char*)d_ws;
    unsigned short* Xbf  = (unsigned short*)ws;            ws += 3145728;
    unsigned short* Wqkv = (unsigned short*)ws;            ws += 2359296;
    unsigned short* Wob  = (unsigned short*)ws;            ws += 786432;
    unsigned short* Qbf  = (unsigned short*)ws;            ws += 2097152;
    unsigned short* Kbf  = (unsigned short*)ws;            ws += 2097152;
    unsigned short* Vtb  = (unsigned short*)ws;            ws += 2097152;
    unsigned short* aob  = (unsigned short*)ws;            ws += 2097152;
    float*          wsfx = (float*)ws;                     ws += 2048;
    unsigned char*  clsg = (unsigned char*)ws;             ws += 2048;

    pack_setup<<<3081, 256, 0, stream>>>(
        (const float4*)x, (const float4*)Wq, (const float4*)Wk,
        (const float4*)Wv, (const float4*)Wo,
        u_bias, v_bias, w_pos,
        (ushort4*)Xbf,
        (ushort4*)Wqkv, (ushort4*)Wqkv + 98304, (ushort4*)Wqkv + 196608,
        (ushort4*)Wob,
        wsfx, clsg);

    gemm_qkv<<<dim3(24, 32), 256, 0, stream>>>(Xbf, Wqkv, u_bias, Qbf, Kbf, Vtb);

    attn_mfma<<<dim3(64, 8, 2), 256, 0, stream>>>(
        Qbf, Kbf, Vtb, w_pos, wsfx, clsg, aob);

    gemm_o<<<dim3(12, 32), 256, 0, stream>>>(aob, Wob, bo, out);
}